// Round 4
// baseline (2833.618 us; speedup 1.0000x reference)
//
#include <hip/hip_runtime.h>

// ---------------------------------------------------------------------------
// RNN_Layer: x[B,T,C] fp32 -> conv1x1(w_in) -> dense(kernel) -> LSTM(rec)
//            -> dense(w_out).  B=32 T=1024 C=512 D=256 U=256 O=256.
// R10: test of the spill hypothesis.  R6/R7/R8 all reported VGPR_Count
// 124-128 while pinning 192 W regs -> W was scratch-spilled and reloaded
// every step (~+70% time, consistent across all three).  The 2-wave/SIMD
// 256-reg budget was never honored.  This round: 256 thr/WG (4 waves,
// 1 wave/SIMD, waves_per_eu(1,1)) -> 512-reg budget; demand ~444 (12
// resident strips = 384 W regs + grouped acc 16 + misc) leaves 68 slack.
// Structure (R7-verified math): wave w owns strips 16w..16w+15 (16 cols
// each); 12 resident in VGPRs, 4 streamed from 128 KiB LDS.  A-frag = h
// broadcast (all 16 rows equal h -> D row0 = z, lanes q==0 hold z[col]).
// Gates: 1 unit/thread via zsh[1024] LDS; 2 lgkm-only barriers/step.
// ---------------------------------------------------------------------------

#define DEV static __device__ __forceinline__

typedef __attribute__((ext_vector_type(8))) short short8;
typedef __attribute__((ext_vector_type(4))) float floatx4;
typedef _Float16 half8 __attribute__((ext_vector_type(8)));

static constexpr int Bsz = 32, T = 1024, C = 512, D = 256, U = 256, FU = 1024;
static constexpr int M = Bsz * T;   // 32768 rows for all GEMMs

DEV float bfu2f(unsigned int u) { union { unsigned int i; float f; } v; v.i = u; return v.f; }
DEV float bf2f(unsigned short u) { return bfu2f(((unsigned int)u) << 16); }
DEV unsigned short f2bf(float f) {
    union { float f; unsigned int i; } v; v.f = f;
    return (unsigned short)((v.i + 0x7fffu + ((v.i >> 16) & 1u)) >> 16);
}
DEV float sigmf(float x) { return 1.0f / (1.0f + __expf(-x)); }
DEV float tanhfast(float x) {
    const float a = __expf(-2.0f * fabsf(x));
    const float t = (1.0f - a) / (1.0f + a);
    return copysignf(t, x);
}
DEV half8 h8c(uint4 v) { return __builtin_bit_cast(half8, v); }

// fp32-or-bf16 element -> bf16 bit pattern (GEMM operand loads)
DEV short ld_bf(const float* p) { return (short)f2bf(*p); }
DEV short ld_bf(const unsigned short* p) { return (short)*p; }
DEV short8 ld_frag(const unsigned short* p) { return *(const short8*)p; }
DEV short8 ld_frag(const float* p) {
    short8 v;
#pragma unroll
    for (int j = 0; j < 8; j++) v[j] = (short)f2bf(p[j]);
    return v;
}
DEV float ldxz1(const float* p) { return *p; }
DEV float ldxz1(const unsigned short* p) { return bf2f(*p); }

// lgkm-only barrier: cross-thread data is LDS-only; skip the vmcnt(0) drain
// (xz prefetch loads / hs stores are thread-local and stay in flight).
#define BAR() asm volatile("s_waitcnt lgkmcnt(0)\n\ts_barrier" ::: "memory")

// ---------------------------------------------------------------------------
// Fragment-direct MFMA GEMM:  C[M,N] = A[M,K] @ B[K,N] + bias[N]
// Layouts (m89/m120-verified): A[m=lane&15][k=quad*8+j];
//   B[k=quad*8+j][n=lane&15]; D[m=quad*4+r][n=lane&15]
// ---------------------------------------------------------------------------
template <int K, int N, int MT, int NS, bool OUTF32, typename AT, typename BT>
__global__ __launch_bounds__(64) void gemm_mfma(
    const AT* __restrict__ A,
    const BT* __restrict__ Bm,
    const float* __restrict__ bias,
    void* __restrict__ Cv)
{
    constexpr int KC = K / 32;
    const int lane = threadIdx.x;
    const int quad = lane >> 4, lr = lane & 15;
    constexpr int NSG = N / (16 * NS);
    const int sg = blockIdx.x % NSG;
    const int mb = blockIdx.x / NSG;
    const int n0 = sg * 16 * NS;

    short8 bf[NS][KC];
    float biasv[NS];
#pragma unroll
    for (int s = 0; s < NS; s++) {
        const int n = n0 + s * 16 + lr;
        biasv[s] = bias[n];
#pragma unroll
        for (int kc = 0; kc < KC; kc++) {
            short8 v;
#pragma unroll
            for (int j = 0; j < 8; j++) {
                const int k = kc * 32 + quad * 8 + j;
                v[j] = ld_bf(&Bm[(size_t)k * N + n]);
            }
            bf[s][kc] = v;
        }
    }

    for (int mt = 0; mt < MT; mt++) {
        const int m0 = (mb * MT + mt) * 16;
        const AT* Ap = A + (size_t)(m0 + lr) * K + quad * 8;
        floatx4 acc[NS];
#pragma unroll
        for (int s = 0; s < NS; s++) acc[s] = (floatx4){0.f, 0.f, 0.f, 0.f};
#pragma unroll
        for (int kc = 0; kc < KC; kc++) {
            short8 af = ld_frag(Ap + kc * 32);
#pragma unroll
            for (int s = 0; s < NS; s++)
                acc[s] = __builtin_amdgcn_mfma_f32_16x16x32_bf16(af, bf[s][kc], acc[s], 0, 0, 0);
        }
#pragma unroll
        for (int s = 0; s < NS; s++) {
            const int n = n0 + s * 16 + lr;
#pragma unroll
            for (int r = 0; r < 4; r++) {
                const int m = m0 + quad * 4 + r;
                const float val = acc[s][r] + biasv[s];
                if (OUTF32)
                    ((float*)Cv)[(size_t)m * N + n] = val;
                else
                    ((unsigned short*)Cv)[(size_t)m * N + n] = f2bf(val);
            }
        }
    }
}

// ---------------------------------------------------------------------------
// Pack rec_kernel fp32 [256][1024] -> f16 MFMA B-fragments (R7-verified).
// Pm[(strip*8 + kc)*64 + lane].j = f16( rec[kc*32+(lane>>4)*8+j][strip*16+(lane&15)] )
// ---------------------------------------------------------------------------
__global__ __launch_bounds__(256) void pack_rec_mfma(const float* __restrict__ rec,
                                                     uint4* __restrict__ Pm)
{
    const int idx = blockIdx.x * 256 + threadIdx.x;   // 0..32767
    const int lane = idx & 63;
    const int kc = (idx >> 6) & 7;
    const int strip = idx >> 9;
    const int q = lane >> 4, lr = lane & 15;
    const int col = strip * 16 + lr;
    const int k0 = kc * 32 + q * 8;
    union { unsigned short u[8]; uint4 v; } out;
#pragma unroll
    for (int j = 0; j < 8; j++) {
        const _Float16 h = (_Float16)rec[(size_t)(k0 + j) * FU + col];
        out.u[j] = __builtin_bit_cast(unsigned short, h);
    }
    Pm[idx] = out.v;
}

// ---------------------------------------------------------------------------
// MFMA LSTM, 4-wave variant. 1 WG (256 thr, 1 wave/SIMD, 512-reg budget)
// per batch. Wave w: strips 16w..16w+11 resident (384 VGPR, pinned),
// strips 16w+12..16w+15 streamed from LDS.  Per step: 4 groups x (8 kc x
// 4 MFMA); z published to zsh; gates 1 unit/thread; h via single LDS f16
// buffer (safe: writes sit strictly between the two barriers).
// ---------------------------------------------------------------------------
template <typename XZT>
__global__ __attribute__((amdgpu_flat_work_group_size(256, 256),
                          amdgpu_waves_per_eu(1, 1)))
void lstm_mfma4(
    const XZT* __restrict__ xz,            // [B, T, 4U]
    const uint4* __restrict__ Pm,          // packed rec frags, 64 strips
    unsigned short* __restrict__ hs)       // [B, T, U] bf16 out
{
    const int b = blockIdx.x;
    const int tid = threadIdx.x;
    const int w = tid >> 6;                // wave 0..3
    const int lane = tid & 63;
    const int q = lane >> 4, lr = lane & 15;
    const int u = tid;                     // unit owned in gate phase

    __shared__ uint4 Wls[16 * 8 * 64];     // streamed strips: 128 KiB
    __shared__ float zsh[FU];              // z scratch: 4 KiB
    __shared__ __align__(16) unsigned short h_pk[U];   // h f16: 512 B

    // stage streamed strips: LDS slot (gw*4+sl) <- global strip 16*gw+12+sl
    for (int i = tid; i < 16 * 8 * 64; i += 256) {
        const int slot = i >> 9;
        const int gs = 16 * (slot >> 2) + 12 + (slot & 3);
        Wls[i] = Pm[(size_t)gs * 512 + (i & 511)];
    }
    if (tid < 128) ((unsigned int*)h_pk)[tid] = 0;

    // resident strips 16w .. 16w+11: 12 x 8 x uint4 = 384 VGPRs
    uint4 Wr[12][8];
#pragma unroll
    for (int s = 0; s < 12; s++)
#pragma unroll
        for (int kc = 0; kc < 8; kc++)
            Wr[s][kc] = Pm[((size_t)(16 * w + s) * 8 + kc) * 64 + lane];
    // opaque pin: asm is the producer -> no remat of the global loads inside
    // the t-loop; with the 512-reg budget there is room to hold all of them.
#pragma unroll
    for (int s = 0; s < 12; s++)
#pragma unroll
        for (int kc = 0; kc < 8; kc++)
            asm volatile("" : "+v"(Wr[s][kc].x), "+v"(Wr[s][kc].y),
                             "+v"(Wr[s][kc].z), "+v"(Wr[s][kc].w));
    __syncthreads();

    const XZT* xzb = xz + (size_t)b * T * FU;
    unsigned short* hsb = hs + (size_t)b * T * U;
    const char* hp = (const char*)h_pk;

    float cst = 0.f;
    float xzi = ldxz1(xzb + u),       xzf = ldxz1(xzb + 256 + u);
    float xzg = ldxz1(xzb + 512 + u), xzo = ldxz1(xzb + 768 + u);

    for (int t = 0; t < T; t++) {
        // prefetch next step's xz (global, stays in flight across BARs)
        float xzi_n = 0.f, xzf_n = 0.f, xzg_n = 0.f, xzo_n = 0.f;
        if (t + 1 < T) {
            const XZT* xt = xzb + (size_t)(t + 1) * FU;
            xzi_n = ldxz1(xt + u);       xzf_n = ldxz1(xt + 256 + u);
            xzg_n = ldxz1(xt + 512 + u); xzo_n = ldxz1(xt + 768 + u);
        }

        // ---- GEMV: 3 resident groups + 1 streamed group of 4 strips ----
#pragma unroll
        for (int g = 0; g < 3; g++) {
            floatx4 ac0 = {0.f,0.f,0.f,0.f}, ac1 = {0.f,0.f,0.f,0.f};
            floatx4 ac2 = {0.f,0.f,0.f,0.f}, ac3 = {0.f,0.f,0.f,0.f};
#pragma unroll
            for (int kc = 0; kc < 8; kc++) {
                // A-frag: 4-way broadcast read of h[kc*32+q*8 .. +7] (f16)
                const uint4 af = *(const uint4*)(hp + kc * 64 + q * 16);
                ac0 = __builtin_amdgcn_mfma_f32_16x16x32_f16(h8c(af), h8c(Wr[g * 4 + 0][kc]), ac0, 0, 0, 0);
                ac1 = __builtin_amdgcn_mfma_f32_16x16x32_f16(h8c(af), h8c(Wr[g * 4 + 1][kc]), ac1, 0, 0, 0);
                ac2 = __builtin_amdgcn_mfma_f32_16x16x32_f16(h8c(af), h8c(Wr[g * 4 + 2][kc]), ac2, 0, 0, 0);
                ac3 = __builtin_amdgcn_mfma_f32_16x16x32_f16(h8c(af), h8c(Wr[g * 4 + 3][kc]), ac3, 0, 0, 0);
            }
            if (q == 0) {
                zsh[(16 * w + g * 4 + 0) * 16 + lr] = ac0[0];
                zsh[(16 * w + g * 4 + 1) * 16 + lr] = ac1[0];
                zsh[(16 * w + g * 4 + 2) * 16 + lr] = ac2[0];
                zsh[(16 * w + g * 4 + 3) * 16 + lr] = ac3[0];
            }
        }
        {
            floatx4 ac0 = {0.f,0.f,0.f,0.f}, ac1 = {0.f,0.f,0.f,0.f};
            floatx4 ac2 = {0.f,0.f,0.f,0.f}, ac3 = {0.f,0.f,0.f,0.f};
#pragma unroll
            for (int kc = 0; kc < 8; kc++) {
                const uint4 af = *(const uint4*)(hp + kc * 64 + q * 16);
                const uint4 w0 = Wls[((w * 4 + 0) * 8 + kc) * 64 + lane];
                const uint4 w1 = Wls[((w * 4 + 1) * 8 + kc) * 64 + lane];
                const uint4 w2 = Wls[((w * 4 + 2) * 8 + kc) * 64 + lane];
                const uint4 w3 = Wls[((w * 4 + 3) * 8 + kc) * 64 + lane];
                ac0 = __builtin_amdgcn_mfma_f32_16x16x32_f16(h8c(af), h8c(w0), ac0, 0, 0, 0);
                ac1 = __builtin_amdgcn_mfma_f32_16x16x32_f16(h8c(af), h8c(w1), ac1, 0, 0, 0);
                ac2 = __builtin_amdgcn_mfma_f32_16x16x32_f16(h8c(af), h8c(w2), ac2, 0, 0, 0);
                ac3 = __builtin_amdgcn_mfma_f32_16x16x32_f16(h8c(af), h8c(w3), ac3, 0, 0, 0);
            }
            if (q == 0) {
                zsh[(16 * w + 12) * 16 + lr] = ac0[0];
                zsh[(16 * w + 13) * 16 + lr] = ac1[0];
                zsh[(16 * w + 14) * 16 + lr] = ac2[0];
                zsh[(16 * w + 15) * 16 + lr] = ac3[0];
            }
        }
        BAR();   // z published; all pre-barrier LDS ops (incl. h reads) done

        // ---- gates: unit u (Keras order i,f,g,o) ----
        const float iv = sigmf(zsh[u] + xzi);
        const float fv = sigmf(zsh[u + 256] + xzf);
        const float gv = tanhfast(zsh[u + 512] + xzg);
        const float ov = sigmf(zsh[u + 768] + xzo);
        cst = fv * cst + iv * gv;
        const float hv = ov * tanhfast(cst);
        h_pk[u] = __builtin_bit_cast(unsigned short, (_Float16)hv);
        hsb[(size_t)t * U + u] = f2bf(hv);
        BAR();   // h published

        xzi = xzi_n; xzf = xzf_n; xzg = xzg_n; xzo = xzo_n;
    }
}

// ---------------------------------------------------------------------------
extern "C" void kernel_launch(void* const* d_in, const int* in_sizes, int n_in,
                              void* d_out, int out_size, void* d_ws, size_t ws_size,
                              hipStream_t stream)
{
    const float* x    = (const float*)d_in[0];
    const float* w_in = (const float*)d_in[1];
    const float* b_in = (const float*)d_in[2];
    const float* kern = (const float*)d_in[3];
    const float* rec  = (const float*)d_in[4];
    const float* bias = (const float*)d_in[5];
    const float* wout = (const float*)d_in[6];
    const float* bout = (const float*)d_in[7];

    char* ws = (char*)d_ws;
    const size_t rec_bytes = (size_t)64 * 8 * 64 * 16;    // 512 KiB packed W frags
    const size_t xin_bytes = (size_t)M * D * 2;           // 16 MiB
    const size_t hs_bytes  = (size_t)M * U * 2;           // 16 MiB
    const size_t xz32_bytes = (size_t)M * FU * 4;         // 128 MiB
    const size_t base = rec_bytes + xin_bytes + hs_bytes;

    uint4* Pm = (uint4*)ws;
    unsigned short* xin_bf = (unsigned short*)(ws + rec_bytes);
    unsigned short* hs_bf  = (unsigned short*)(ws + rec_bytes + xin_bytes);
    char* xz_raw = ws + base;

    const bool use_f32 = ws_size >= base + xz32_bytes;

    // pack rec_kernel -> f16 MFMA fragment layout (every launch; ws re-poisoned)
    pack_rec_mfma<<<128, 256, 0, stream>>>(rec, Pm);

    // GEMM1: xin = bf16(x @ w_in + b_in)   [M,512]x[512,256]
    gemm_mfma<512, 256, 16, 2, false><<<(256 / 32) * (M / 256), 64, 0, stream>>>(
        x, w_in, b_in, (void*)xin_bf);

    if (use_f32) {
        float* xzp = (float*)xz_raw;
        // GEMM2: xz = fp32(xin @ kernel + bias)  [M,256]x[256,1024]
        gemm_mfma<256, 1024, 16, 2, true><<<(1024 / 32) * (M / 256), 64, 0, stream>>>(
            xin_bf, kern, bias, (void*)xzp);
        lstm_mfma4<float><<<Bsz, 256, 0, stream>>>(xzp, Pm, hs_bf);
    } else {
        unsigned short* xzp = (unsigned short*)xz_raw;
        gemm_mfma<256, 1024, 16, 2, false><<<(1024 / 32) * (M / 256), 64, 0, stream>>>(
            xin_bf, kern, bias, (void*)xzp);
        lstm_mfma4<unsigned short><<<Bsz, 256, 0, stream>>>(xzp, Pm, hs_bf);
    }

    // GEMM3: out = fp32(hs @ w_out + b_out)  [M,256]x[256,256]
    gemm_mfma<256, 256, 16, 2, true><<<(256 / 32) * (M / 256), 64, 0, stream>>>(
        hs_bf, wout, bout, d_out);
}